// Round 2
// baseline (42.581 us; speedup 1.0000x reference)
//
#include <hip/hip_runtime.h>
#include <hip/hip_bf16.h>

typedef __bf16 bf16x8 __attribute__((ext_vector_type(8)));
typedef float  f32x4  __attribute__((ext_vector_type(4)));

#define NFEAT 128
#define NSAMP 8192
#define GROUPS 64
#define FEAT_PER_GRP 2
#define MT_PER_WAVE 8   // 8 M-tiles of 16 samples = 128 samples per wave

// Fragment layout (mfma_f32_16x16x32_bf16), verified in round 1:
//   A: lane l holds A[row = l&15][kslot = 8*(l>>4) + j], j = 0..7
//   B: lane l holds B[kslot = 8*(l>>4) + j][col = l&15]
//   D: lane l reg r holds D[row = 4*(l>>4) + r][col = l&15]
// K-permutation pi(ks,g,j) = 32*ks + 16*(j>>2) + 4*g + (j&3) lets a D-layout
// value (row = 16*mt + 4*g + r) feed the next layer's B-fragment in-lane.

// ---------------------------------------------------------------------------
// Prep: pack W0|b0 (layer-1 A-fragments), W1^T (pi-K), W2^T (pi-K), and
// transpose X -> Xt[f][n].
// ---------------------------------------------------------------------------
__global__ __launch_bounds__(256) void nam_prep(
    const float* __restrict__ X,  const float* __restrict__ W0,
    const float* __restrict__ b0, const float* __restrict__ W1,
    const float* __restrict__ W2, __bf16* __restrict__ W0p,
    __bf16* __restrict__ W1p, __bf16* __restrict__ W2p,
    float* __restrict__ Xt) {
  int t = blockIdx.x * 256 + threadIdx.x;
  const int n1 = NFEAT * 8 * 64 * 8;            // 524288: W1p
  const int n2 = NFEAT * 4 * 64 * 8;            // 262144: W2p
  const int n3 = NFEAT * 4 * 64 * 8;            // 262144: W0p
  if (t < n1) {
    int j = t & 7, l = (t >> 3) & 63, q = (t >> 9) & 7, f = t >> 12;
    int mt = q >> 1, ks = q & 1;
    int out2 = (l & 15) + 16 * mt;
    int g = l >> 4;
    int i1 = 32 * ks + 16 * (j >> 2) + 4 * g + (j & 3);   // pi-permuted K
    W1p[t] = (__bf16)W1[f * 4096 + i1 * 64 + out2];
  } else if (t < n1 + n2) {
    int t2 = t - n1;
    int j = t2 & 7, l = (t2 >> 3) & 63, q = (t2 >> 9) & 3, f = t2 >> 11;
    int mt3 = q >> 1, ks = q & 1;
    int out3 = (l & 15) + 16 * mt3;
    int g = l >> 4;
    int i2 = 32 * ks + 16 * (j >> 2) + 4 * g + (j & 3);   // pi-permuted K
    W2p[t2] = (__bf16)W2[f * 2048 + i2 * 32 + out3];
  } else if (t < n1 + n2 + n3) {
    int t3 = t - n1 - n2;
    int j = t3 & 7, l = (t3 >> 3) & 63, mt1 = (t3 >> 9) & 3, f = t3 >> 11;
    int ls = l & 15, g = l >> 4;
    int k = 8 * g + j;                                    // layer-1 K index
    int out1 = 16 * mt1 + ls;
    float v = 0.f;
    if (k == 0) v = W0[f * 64 + out1];
    else if (k == 1) v = b0[f * 64 + out1];
    W0p[t3] = (__bf16)v;
  } else {
    int t4 = t - n1 - n2 - n3;                            // 1048576: Xt
    int n = t4 & (NSAMP - 1), f = t4 >> 13;
    Xt[t4] = X[n * NFEAT + f];
  }
}

// ---------------------------------------------------------------------------
// Main: one wave per block, 128 samples x 2 features. All three layers MFMA,
// swapped orientation D[out][sample]; zero cross-lane traffic, zero LDS.
// ---------------------------------------------------------------------------
__global__ __launch_bounds__(64, 3) void nam_main(
    const float* __restrict__ Xt, const float* __restrict__ b1,
    const float* __restrict__ b2, const float* __restrict__ W3,
    const float* __restrict__ b3, const bf16x8* __restrict__ W0p,
    const bf16x8* __restrict__ W1p, const bf16x8* __restrict__ W2p,
    float* __restrict__ part) {
  const int l  = threadIdx.x;            // 0..63
  const int lg = l >> 4, ls = l & 15;
  const int blk   = blockIdx.x;
  const int chunk = blk & 63;            // 64 chunks of 128 samples
  const int grp   = blk >> 6;            // 64 feature groups
  const int n0 = chunk * 128;
  const int f0 = grp * FEAT_PER_GRP;

  float acc[MT_PER_WAVE];
#pragma unroll
  for (int m = 0; m < MT_PER_WAVE; ++m) acc[m] = 0.f;

  const f32x4 zc = {0.f, 0.f, 0.f, 0.f};

  for (int ff = 0; ff < FEAT_PER_GRP; ++ff) {
    const int f = f0 + ff;
    // ---- per-feature weight fragments (coalesced 16B/lane) ----
    bf16x8 w0f[4];
#pragma unroll
    for (int q = 0; q < 4; ++q) w0f[q] = W0p[(f * 4 + q) * 64 + l];
    bf16x8 w1f[8];
#pragma unroll
    for (int q = 0; q < 8; ++q) w1f[q] = W1p[(f * 8 + q) * 64 + l];
    bf16x8 w2f[4];
#pragma unroll
    for (int q = 0; q < 4; ++q) w2f[q] = W2p[(f * 4 + q) * 64 + l];
    f32x4 b1f[4], b2f[2], w3f[2];
#pragma unroll
    for (int mt = 0; mt < 4; ++mt)
      b1f[mt] = *(const f32x4*)(b1 + f * 64 + 16 * mt + 4 * lg);
#pragma unroll
    for (int mt = 0; mt < 2; ++mt)
      b2f[mt] = *(const f32x4*)(b2 + f * 32 + 16 * mt + 4 * lg);
#pragma unroll
    for (int mt = 0; mt < 2; ++mt)
      w3f[mt] = *(const f32x4*)(W3 + f * 32 + 16 * mt + 4 * lg);
    const float b3v = b3[f];
    const float* xb = Xt + f * NSAMP + n0;

#pragma unroll
    for (int m = 0; m < MT_PER_WAVE; ++m) {
      const float xv = xb[16 * m + ls];
      // ---- layer-1 B operand: [x; 1] in lanes lg==0, k-slots 0,1 ----
      float x0 = (lg == 0) ? xv : 0.f;
      float x1 = (lg == 0) ? 1.f : 0.f;
      bf16x8 bx = {};
      bx[0] = (__bf16)x0;
      bx[1] = (__bf16)x1;
      // ---- layer 1: D[out1][sample] = w0*x + b0 ----
      f32x4 d1[4];
#pragma unroll
      for (int mt = 0; mt < 4; ++mt)
        d1[mt] = __builtin_amdgcn_mfma_f32_16x16x32_bf16(w0f[mt], bx, zc, 0, 0, 0);
      // ---- relu + pack: D-layout h1 -> L2 B-fragments (pi K) ----
      bf16x8 a1[2];
#pragma unroll
      for (int ks = 0; ks < 2; ++ks)
#pragma unroll
        for (int j = 0; j < 8; ++j) {
          float v = d1[2 * ks + (j >> 2)][j & 3];
          a1[ks][j] = (__bf16)fmaxf(v, 0.f);
        }
      // ---- layer 2: D[out2][sample], C-init = b1 ----
      f32x4 h2[4];
#pragma unroll
      for (int mt = 0; mt < 4; ++mt) {
        f32x4 c = b1f[mt];
        c = __builtin_amdgcn_mfma_f32_16x16x32_bf16(w1f[mt * 2 + 0], a1[0], c, 0, 0, 0);
        c = __builtin_amdgcn_mfma_f32_16x16x32_bf16(w1f[mt * 2 + 1], a1[1], c, 0, 0, 0);
        h2[mt] = c;
      }
      // ---- relu + pack: h2 -> L3 B-fragments (pi K) ----
      bf16x8 bfr[2];
#pragma unroll
      for (int ks = 0; ks < 2; ++ks)
#pragma unroll
        for (int j = 0; j < 8; ++j) {
          float v = h2[2 * ks + (j >> 2)][j & 3];
          bfr[ks][j] = (__bf16)fmaxf(v, 0.f);
        }
      // ---- layer 3: D[out3][sample], C-init = b2 ----
      f32x4 h3[2];
#pragma unroll
      for (int mt = 0; mt < 2; ++mt) {
        f32x4 c = b2f[mt];
        c = __builtin_amdgcn_mfma_f32_16x16x32_bf16(w2f[mt * 2 + 0], bfr[0], c, 0, 0, 0);
        c = __builtin_amdgcn_mfma_f32_16x16x32_bf16(w2f[mt * 2 + 1], bfr[1], c, 0, 0, 0);
        h3[mt] = c;
      }
      // ---- epilogue: relu, dot with w3 (per-lane partial over 8 outs) ----
      float p = (lg == 0) ? b3v : 0.f;
#pragma unroll
      for (int mt = 0; mt < 2; ++mt)
#pragma unroll
        for (int r = 0; r < 4; ++r)
          p = fmaf(fmaxf(h3[mt][r], 0.f), w3f[mt][r], p);
      acc[m] += p;
    }
  }
  // ---- reduce partial contribs across the 4 lane-groups, store ----
#pragma unroll
  for (int m = 0; m < MT_PER_WAVE; ++m) {
    float v = acc[m];
    v += __shfl_xor(v, 16, 64);
    v += __shfl_xor(v, 32, 64);
    if (l < 16) part[grp * NSAMP + n0 + 16 * m + l] = v;
  }
}

// ---------------------------------------------------------------------------
// Reduce: out[n] = bias + sum_g part[g][n]. float4 over samples, 4-way group
// split + LDS combine. Fixed order -> deterministic.
// ---------------------------------------------------------------------------
__global__ __launch_bounds__(256) void nam_reduce(const float* __restrict__ part,
                                                  const float* __restrict__ bias,
                                                  float* __restrict__ out) {
  int tid = threadIdx.x;
  int quad = blockIdx.x * 64 + (tid & 63);   // which float4 of samples
  int gs = tid >> 6;                         // 0..3 group split
  f32x4 s = {0.f, 0.f, 0.f, 0.f};
#pragma unroll
  for (int g = gs * 16; g < gs * 16 + 16; ++g)
    s += *(const f32x4*)(part + (size_t)g * NSAMP + quad * 4);
  __shared__ f32x4 red[256];
  red[tid] = s;
  __syncthreads();
  if (gs == 0) {
    f32x4 t = red[tid] + red[tid + 64] + red[tid + 128] + red[tid + 192];
    float bv = bias[0];
    t[0] += bv; t[1] += bv; t[2] += bv; t[3] += bv;
    *(f32x4*)(out + quad * 4) = t;
  }
}

// ---------------------------------------------------------------------------
// Fallback (only if ws too small): naive fp32, correct but slow.
// ---------------------------------------------------------------------------
__global__ void nam_naive(const float* __restrict__ X, const float* __restrict__ W0,
                          const float* __restrict__ b0, const float* __restrict__ W1,
                          const float* __restrict__ b1, const float* __restrict__ W2,
                          const float* __restrict__ b2, const float* __restrict__ W3,
                          const float* __restrict__ b3, const float* __restrict__ bias,
                          float* __restrict__ out) {
  int n = blockIdx.x * 64 + threadIdx.x;
  if (n >= NSAMP) return;
  float s = bias[0];
  for (int f = 0; f < NFEAT; ++f) {
    float xv = X[n * NFEAT + f];
    float h1[64], h2[64];
    for (int i = 0; i < 64; ++i)
      h1[i] = fmaxf(fmaf(xv, W0[f * 64 + i], b0[f * 64 + i]), 0.f);
    for (int k = 0; k < 64; ++k) {
      float t = b1[f * 64 + k];
      for (int i = 0; i < 64; ++i) t = fmaf(h1[i], W1[f * 4096 + i * 64 + k], t);
      h2[k] = fmaxf(t, 0.f);
    }
    float c = b3[f];
    for (int k = 0; k < 32; ++k) {
      float t = b2[f * 32 + k];
      for (int i = 0; i < 64; ++i) t = fmaf(h2[i], W2[f * 2048 + i * 32 + k], t);
      c = fmaf(fmaxf(t, 0.f), W3[f * 32 + k], c);
    }
    s += c;
  }
  out[n] = s;
}

extern "C" void kernel_launch(void* const* d_in, const int* in_sizes, int n_in,
                              void* d_out, int out_size, void* d_ws, size_t ws_size,
                              hipStream_t stream) {
  const float* X    = (const float*)d_in[0];
  const float* W0   = (const float*)d_in[1];
  const float* b0   = (const float*)d_in[2];
  const float* W1   = (const float*)d_in[3];
  const float* b1   = (const float*)d_in[4];
  const float* W2   = (const float*)d_in[5];
  const float* b2   = (const float*)d_in[6];
  const float* W3   = (const float*)d_in[7];
  const float* b3   = (const float*)d_in[8];
  const float* bias = (const float*)d_in[9];
  float* out = (float*)d_out;

  const size_t W1P_BYTES  = (size_t)NFEAT * 8 * 64 * 16;   // 1 MiB
  const size_t W2P_BYTES  = (size_t)NFEAT * 4 * 64 * 16;   // 512 KiB
  const size_t W0P_BYTES  = (size_t)NFEAT * 4 * 64 * 16;   // 512 KiB
  const size_t XT_BYTES   = (size_t)NFEAT * NSAMP * 4;     // 4 MiB
  const size_t PART_BYTES = (size_t)GROUPS * NSAMP * 4;    // 2 MiB
  const size_t NEED = W1P_BYTES + W2P_BYTES + W0P_BYTES + XT_BYTES + PART_BYTES;
  if (ws_size < NEED) {
    nam_naive<<<NSAMP / 64, 64, 0, stream>>>(X, W0, b0, W1, b1, W2, b2, W3, b3, bias, out);
    return;
  }
  char* wsb = (char*)d_ws;
  __bf16* W1p = (__bf16*)wsb;
  __bf16* W2p = (__bf16*)(wsb + W1P_BYTES);
  __bf16* W0p = (__bf16*)(wsb + W1P_BYTES + W2P_BYTES);
  float*  Xt  = (float*)(wsb + W1P_BYTES + W2P_BYTES + W0P_BYTES);
  float*  partb = (float*)(wsb + W1P_BYTES + W2P_BYTES + W0P_BYTES + XT_BYTES);

  const int prep_threads = NFEAT * 8 * 64 * 8 + 2 * (NFEAT * 4 * 64 * 8) + NFEAT * NSAMP;
  nam_prep<<<prep_threads / 256, 256, 0, stream>>>(X, W0, b0, W1, W2, W0p, W1p, W2p, Xt);
  nam_main<<<GROUPS * 64, 64, 0, stream>>>(Xt, b1, b2, W3, b3,
                                           (const bf16x8*)W0p, (const bf16x8*)W1p,
                                           (const bf16x8*)W2p, partb);
  nam_reduce<<<(NSAMP / 4) / 64, 256, 0, stream>>>(partb, bias, out);
}

// Round 3
// 39.760 us; speedup vs baseline: 1.0710x; 1.0710x over previous
//
#include <hip/hip_runtime.h>
#include <hip/hip_bf16.h>

typedef __bf16 bf16x8 __attribute__((ext_vector_type(8)));
typedef float  f32x4  __attribute__((ext_vector_type(4)));

#define NFEAT 128
#define NSAMP 8192
#define GROUPS 64     // feature groups, 2 features each
#define MT 8          // 8 M-tiles of 16 samples = 128 samples per wave

// Fragment layout (mfma_f32_16x16x32_bf16), verified rounds 1-2:
//   A: lane l holds A[row = l&15][kslot = 8*(l>>4) + j], j = 0..7
//   B: lane l holds B[kslot = 8*(l>>4) + j][col = l&15]
//   D: lane l reg r holds D[row = 4*(l>>4) + r][col = l&15]
// K-permutation pi(ks,g,j) = 32*ks + 16*(j>>2) + 4*g + (j&3) lets D-layout
// values (row = 16*mt + 4*g + r) feed the next layer's B-fragment in-lane.

// ---------------------------------------------------------------------------
// Main: one wave per block, 128 samples x 2 features. Weights packed
// in-register per wave (no prep dispatch). All 3 layers MFMA, swapped
// orientation D[out][sample]; no LDS, no cross-lane traffic.
// ---------------------------------------------------------------------------
__global__ __launch_bounds__(64) void nam_main(
    const float* __restrict__ X,  const float* __restrict__ W0,
    const float* __restrict__ b0, const float* __restrict__ W1,
    const float* __restrict__ b1, const float* __restrict__ W2,
    const float* __restrict__ b2, const float* __restrict__ W3,
    const float* __restrict__ b3, float* __restrict__ part) {
  const int l  = threadIdx.x;            // 0..63
  const int lg = l >> 4, ls = l & 15;
  const int chunk = blockIdx.x & 63;     // 64 chunks of 128 samples
  const int grp   = blockIdx.x >> 6;     // 64 feature groups
  const int n0 = chunk * 128;
  const int f0 = grp * 2;

  float acc[MT];
#pragma unroll
  for (int m = 0; m < MT; ++m) acc[m] = 0.f;
  const f32x4 zc = {0.f, 0.f, 0.f, 0.f};

  for (int ff = 0; ff < 2; ++ff) {
    const int f = f0 + ff;
    // ---- pack W1^T fragments in-register (pi-permuted K) ----
    const float* w1b = W1 + f * 4096 + ls;   // + i1*64 + 16*mt
    bf16x8 w1f[8];
#pragma unroll
    for (int mt = 0; mt < 4; ++mt)
#pragma unroll
      for (int ks = 0; ks < 2; ++ks) {
        bf16x8 v;
#pragma unroll
        for (int j = 0; j < 8; ++j) {
          int i1 = 32 * ks + 16 * (j >> 2) + 4 * lg + (j & 3);
          v[j] = (__bf16)w1b[i1 * 64 + 16 * mt];
        }
        w1f[mt * 2 + ks] = v;
      }
    // ---- pack W2^T fragments in-register (pi-permuted K) ----
    const float* w2b = W2 + f * 2048 + ls;   // + i2*32 + 16*mt
    bf16x8 w2f[4];
#pragma unroll
    for (int mt = 0; mt < 2; ++mt)
#pragma unroll
      for (int ks = 0; ks < 2; ++ks) {
        bf16x8 v;
#pragma unroll
        for (int j = 0; j < 8; ++j) {
          int i2 = 32 * ks + 16 * (j >> 2) + 4 * lg + (j & 3);
          v[j] = (__bf16)w2b[i2 * 32 + 16 * mt];
        }
        w2f[mt * 2 + ks] = v;
      }
    // ---- layer-1 A fragments: k=0 -> w0, k=1 -> b0 (lg==0 lanes only) ----
    bf16x8 w0f[4];
#pragma unroll
    for (int mt = 0; mt < 4; ++mt) {
      bf16x8 v = {};
      if (lg == 0) {
        v[0] = (__bf16)W0[f * 64 + 16 * mt + ls];
        v[1] = (__bf16)b0[f * 64 + 16 * mt + ls];
      }
      w0f[mt] = v;
    }
    // ---- bias / head fragments (D-layout, broadcast across ls) ----
    f32x4 b1f[4], b2f[2], w3f[2];
#pragma unroll
    for (int mt = 0; mt < 4; ++mt)
      b1f[mt] = *(const f32x4*)(b1 + f * 64 + 16 * mt + 4 * lg);
#pragma unroll
    for (int mt = 0; mt < 2; ++mt)
      b2f[mt] = *(const f32x4*)(b2 + f * 32 + 16 * mt + 4 * lg);
#pragma unroll
    for (int mt = 0; mt < 2; ++mt)
      w3f[mt] = *(const f32x4*)(W3 + f * 32 + 16 * mt + 4 * lg);
    const float b3v = b3[f];
    const float* xb = X + (size_t)n0 * NFEAT + f;

#pragma unroll
    for (int m = 0; m < MT; ++m) {
      // 16-lane broadcast gather (stride 512B, L2/L3-resident, hoisted)
      const float xv = xb[(16 * m + ls) * NFEAT];
      // ---- layer-1 B operand: [x; 1] in k-slots 0,1 (lg==0 lanes) ----
      bf16x8 bx = {};
      bx[0] = (lg == 0) ? (__bf16)xv : (__bf16)0.f;
      bx[1] = (lg == 0) ? (__bf16)1.f : (__bf16)0.f;
      // ---- layer 1: D[out1][sample] = w0*x + b0 ----
      f32x4 d1[4];
#pragma unroll
      for (int mt = 0; mt < 4; ++mt)
        d1[mt] = __builtin_amdgcn_mfma_f32_16x16x32_bf16(w0f[mt], bx, zc, 0, 0, 0);
      // ---- relu + pack: D-layout h1 -> L2 B-fragments (pi K) ----
      bf16x8 a1[2];
#pragma unroll
      for (int ks = 0; ks < 2; ++ks)
#pragma unroll
        for (int j = 0; j < 8; ++j) {
          float v = d1[2 * ks + (j >> 2)][j & 3];
          a1[ks][j] = (__bf16)fmaxf(v, 0.f);
        }
      // ---- layer 2: D[out2][sample], C-init = b1 ----
      f32x4 h2[4];
#pragma unroll
      for (int mt = 0; mt < 4; ++mt) {
        f32x4 c = b1f[mt];
        c = __builtin_amdgcn_mfma_f32_16x16x32_bf16(w1f[mt * 2 + 0], a1[0], c, 0, 0, 0);
        c = __builtin_amdgcn_mfma_f32_16x16x32_bf16(w1f[mt * 2 + 1], a1[1], c, 0, 0, 0);
        h2[mt] = c;
      }
      // ---- relu + pack: h2 -> L3 B-fragments (pi K) ----
      bf16x8 bfr[2];
#pragma unroll
      for (int ks = 0; ks < 2; ++ks)
#pragma unroll
        for (int j = 0; j < 8; ++j) {
          float v = h2[2 * ks + (j >> 2)][j & 3];
          bfr[ks][j] = (__bf16)fmaxf(v, 0.f);
        }
      // ---- layer 3: D[out3][sample], C-init = b2 ----
      f32x4 h3[2];
#pragma unroll
      for (int mt = 0; mt < 2; ++mt) {
        f32x4 c = b2f[mt];
        c = __builtin_amdgcn_mfma_f32_16x16x32_bf16(w2f[mt * 2 + 0], bfr[0], c, 0, 0, 0);
        c = __builtin_amdgcn_mfma_f32_16x16x32_bf16(w2f[mt * 2 + 1], bfr[1], c, 0, 0, 0);
        h3[mt] = c;
      }
      // ---- epilogue: relu, dot with w3 (two chains to shorten dep path) ----
      float p0 = (lg == 0) ? b3v : 0.f, p1 = 0.f;
#pragma unroll
      for (int r = 0; r < 4; ++r) {
        p0 = fmaf(fmaxf(h3[0][r], 0.f), w3f[0][r], p0);
        p1 = fmaf(fmaxf(h3[1][r], 0.f), w3f[1][r], p1);
      }
      acc[m] += p0 + p1;
    }
  }
  // ---- reduce partial contribs across the 4 lane-groups, store ----
#pragma unroll
  for (int m = 0; m < MT; ++m) {
    float v = acc[m];
    v += __shfl_xor(v, 16, 64);
    v += __shfl_xor(v, 32, 64);
    if (l < 16) part[grp * NSAMP + n0 + 16 * m + l] = v;
  }
}

// ---------------------------------------------------------------------------
// Reduce: out[n] = bias + sum_g part[g][n]. float4 over samples, 4-way group
// split + LDS combine. Fixed order -> deterministic.
// ---------------------------------------------------------------------------
__global__ __launch_bounds__(256) void nam_reduce(const float* __restrict__ part,
                                                  const float* __restrict__ bias,
                                                  float* __restrict__ out) {
  int tid = threadIdx.x;
  int quad = blockIdx.x * 64 + (tid & 63);   // which float4 of samples
  int gs = tid >> 6;                         // 0..3 group split
  f32x4 s = {0.f, 0.f, 0.f, 0.f};
#pragma unroll
  for (int g = gs * 16; g < gs * 16 + 16; ++g)
    s += *(const f32x4*)(part + (size_t)g * NSAMP + quad * 4);
  __shared__ f32x4 red[256];
  red[tid] = s;
  __syncthreads();
  if (gs == 0) {
    f32x4 t = red[tid] + red[tid + 64] + red[tid + 128] + red[tid + 192];
    float bv = bias[0];
    t[0] += bv; t[1] += bv; t[2] += bv; t[3] += bv;
    *(f32x4*)(out + quad * 4) = t;
  }
}

// ---------------------------------------------------------------------------
// Fallback (only if ws too small): naive fp32, correct but slow.
// ---------------------------------------------------------------------------
__global__ void nam_naive(const float* __restrict__ X, const float* __restrict__ W0,
                          const float* __restrict__ b0, const float* __restrict__ W1,
                          const float* __restrict__ b1, const float* __restrict__ W2,
                          const float* __restrict__ b2, const float* __restrict__ W3,
                          const float* __restrict__ b3, const float* __restrict__ bias,
                          float* __restrict__ out) {
  int n = blockIdx.x * 64 + threadIdx.x;
  if (n >= NSAMP) return;
  float s = bias[0];
  for (int f = 0; f < NFEAT; ++f) {
    float xv = X[n * NFEAT + f];
    float h1[64], h2[64];
    for (int i = 0; i < 64; ++i)
      h1[i] = fmaxf(fmaf(xv, W0[f * 64 + i], b0[f * 64 + i]), 0.f);
    for (int k = 0; k < 64; ++k) {
      float t = b1[f * 64 + k];
      for (int i = 0; i < 64; ++i) t = fmaf(h1[i], W1[f * 4096 + i * 64 + k], t);
      h2[k] = fmaxf(t, 0.f);
    }
    float c = b3[f];
    for (int k = 0; k < 32; ++k) {
      float t = b2[f * 32 + k];
      for (int i = 0; i < 64; ++i) t = fmaf(h2[i], W2[f * 2048 + i * 32 + k], t);
      c = fmaf(fmaxf(t, 0.f), W3[f * 32 + k], c);
    }
    s += c;
  }
  out[n] = s;
}

extern "C" void kernel_launch(void* const* d_in, const int* in_sizes, int n_in,
                              void* d_out, int out_size, void* d_ws, size_t ws_size,
                              hipStream_t stream) {
  const float* X    = (const float*)d_in[0];
  const float* W0   = (const float*)d_in[1];
  const float* b0   = (const float*)d_in[2];
  const float* W1   = (const float*)d_in[3];
  const float* b1   = (const float*)d_in[4];
  const float* W2   = (const float*)d_in[5];
  const float* b2   = (const float*)d_in[6];
  const float* W3   = (const float*)d_in[7];
  const float* b3   = (const float*)d_in[8];
  const float* bias = (const float*)d_in[9];
  float* out = (float*)d_out;

  const size_t PART_BYTES = (size_t)GROUPS * NSAMP * 4;    // 2 MiB
  if (ws_size < PART_BYTES) {
    nam_naive<<<NSAMP / 64, 64, 0, stream>>>(X, W0, b0, W1, b1, W2, b2, W3, b3, bias, out);
    return;
  }
  float* partb = (float*)d_ws;

  nam_main<<<GROUPS * 64, 64, 0, stream>>>(X, W0, b0, W1, b1, W2, b2, W3, b3, partb);
  nam_reduce<<<(NSAMP / 4) / 64, 256, 0, stream>>>(partb, bias, out);
}

// Round 4
// 33.135 us; speedup vs baseline: 1.2851x; 1.1999x over previous
//
#include <hip/hip_runtime.h>
#include <hip/hip_bf16.h>

typedef __bf16 bf16x8 __attribute__((ext_vector_type(8)));
typedef float  f32x4  __attribute__((ext_vector_type(4)));

#define NFEAT 128
#define NSAMP 8192
#define MT 8          // 8 M-tiles of 16 samples = 128 samples per wave

// Fragment layout (mfma_f32_16x16x32_bf16), verified rounds 1-3:
//   A: lane l holds A[row = l&15][kslot = 8*(l>>4) + j], j = 0..7
//   B: lane l holds B[kslot = 8*(l>>4) + j][col = l&15]
//   D: lane l reg r holds D[row = 4*(l>>4) + r][col = l&15]
// K-permutation pi(ks,g,j) = 32*ks + 16*(j>>2) + 4*g + (j&3) lets D-layout
// values (row = 16*mt + 4*g + r) feed the next layer's B-fragment in-lane.

// ---------------------------------------------------------------------------
// Main: 256-thread block = 4 waves, one feature per block, 4 sample-chunks of
// 128. Weight fragments built cooperatively into LDS once per block; each
// wave then holds them in registers. Layer 1 in VALU (pi-indexed), layers 2/3
// MFMA in swapped orientation D[out][sample].
// ---------------------------------------------------------------------------
__global__ __launch_bounds__(256) void nam_main(
    const float* __restrict__ X,  const float* __restrict__ W0,
    const float* __restrict__ b0, const float* __restrict__ W1,
    const float* __restrict__ b1, const float* __restrict__ W2,
    const float* __restrict__ b2, const float* __restrict__ W3,
    const float* __restrict__ b3, float* __restrict__ part) {
  const int tid = threadIdx.x;
  const int l  = tid & 63;               // lane in wave
  const int w  = tid >> 6;               // wave 0..3
  const int lg = l >> 4, ls = l & 15;
  const int f  = blockIdx.x >> 4;        // one feature per block
  const int cg = blockIdx.x & 15;        // chunk group
  const int n0 = (cg * 4 + w) * 128;     // this wave's 128 samples

  __shared__ __align__(16) __bf16 w1s[8][64][8];   // 8 KiB
  __shared__ __align__(16) __bf16 w2s[4][64][8];   // 4 KiB

  // ---- per-lane layer-1 weights (pi-indexed) + bias/head fragments ----
  float w0p[16], b0p[16];
#pragma unroll
  for (int ks = 0; ks < 2; ++ks)
#pragma unroll
    for (int j = 0; j < 8; ++j) {
      int kp = 32 * ks + 16 * (j >> 2) + 4 * lg + (j & 3);
      w0p[ks * 8 + j] = W0[f * 64 + kp];
      b0p[ks * 8 + j] = b0[f * 64 + kp];
    }
  f32x4 b1f[4], b2f[2], w3f[2];
#pragma unroll
  for (int mt = 0; mt < 4; ++mt)
    b1f[mt] = *(const f32x4*)(b1 + f * 64 + 16 * mt + 4 * lg);
#pragma unroll
  for (int mt = 0; mt < 2; ++mt)
    b2f[mt] = *(const f32x4*)(b2 + f * 32 + 16 * mt + 4 * lg);
#pragma unroll
  for (int mt = 0; mt < 2; ++mt)
    w3f[mt] = *(const f32x4*)(W3 + f * 32 + 16 * mt + 4 * lg);
  const float b3v = b3[f];

  // ---- cooperative fragment build: 768 slots over 256 threads ----
#pragma unroll
  for (int i = 0; i < 3; ++i) {
    int s = tid + 256 * i;
    int arr = (s >= 512);
    int s0 = arr ? s - 512 : s;
    int sl = s0 & 63, q = s0 >> 6;
    int slg = sl >> 4, sls = sl & 15, mt = q >> 1, ks = q & 1;
    const float* base = arr ? (W2 + f * 2048 + 16 * mt + sls)
                            : (W1 + f * 4096 + 16 * mt + sls);
    int stride = arr ? 32 : 64;
    bf16x8 v;
#pragma unroll
    for (int j = 0; j < 8; ++j) {
      int ii = 32 * ks + 16 * (j >> 2) + 4 * slg + (j & 3);
      v[j] = (__bf16)base[ii * stride];
    }
    if (arr) *(bf16x8*)&w2s[q][sl][0] = v;
    else     *(bf16x8*)&w1s[q][sl][0] = v;
  }
  __syncthreads();

  // ---- fragments to registers (conflict-free ds_read_b128) ----
  bf16x8 w1f[8], w2f[4];
#pragma unroll
  for (int q = 0; q < 8; ++q) w1f[q] = *(const bf16x8*)&w1s[q][l][0];
#pragma unroll
  for (int q = 0; q < 4; ++q) w2f[q] = *(const bf16x8*)&w2s[q][l][0];

  const float* xb = X + (size_t)n0 * NFEAT + f;
  float acc[MT];
#pragma unroll
  for (int m = 0; m < MT; ++m) acc[m] = 0.f;

#pragma unroll
  for (int m = 0; m < MT; ++m) {
    const float xv = xb[(16 * m + ls) * NFEAT];   // 16-lane broadcast gather
    // ---- layer 1 in VALU: a1[ks][j] = relu(w0[pi]*x + b0[pi]) ----
    bf16x8 a1[2];
#pragma unroll
    for (int ks = 0; ks < 2; ++ks)
#pragma unroll
      for (int j = 0; j < 8; ++j) {
        float h = fmaf(xv, w0p[ks * 8 + j], b0p[ks * 8 + j]);
        a1[ks][j] = (__bf16)fmaxf(h, 0.f);
      }
    // ---- layer 2: D[out2][sample], C-init = b1 ----
    f32x4 h2[4];
#pragma unroll
    for (int mt = 0; mt < 4; ++mt) {
      f32x4 c = b1f[mt];
      c = __builtin_amdgcn_mfma_f32_16x16x32_bf16(w1f[mt * 2 + 0], a1[0], c, 0, 0, 0);
      c = __builtin_amdgcn_mfma_f32_16x16x32_bf16(w1f[mt * 2 + 1], a1[1], c, 0, 0, 0);
      h2[mt] = c;
    }
    // ---- relu + pack: h2 -> L3 B-fragments (pi K) ----
    bf16x8 bfr[2];
#pragma unroll
    for (int ks = 0; ks < 2; ++ks)
#pragma unroll
      for (int j = 0; j < 8; ++j) {
        float v = h2[2 * ks + (j >> 2)][j & 3];
        bfr[ks][j] = (__bf16)fmaxf(v, 0.f);
      }
    // ---- layer 3: D[out3][sample], C-init = b2 ----
    f32x4 h3[2];
#pragma unroll
    for (int mt = 0; mt < 2; ++mt) {
      f32x4 c = b2f[mt];
      c = __builtin_amdgcn_mfma_f32_16x16x32_bf16(w2f[mt * 2 + 0], bfr[0], c, 0, 0, 0);
      c = __builtin_amdgcn_mfma_f32_16x16x32_bf16(w2f[mt * 2 + 1], bfr[1], c, 0, 0, 0);
      h3[mt] = c;
    }
    // ---- epilogue: relu, dot with w3 (two chains) ----
    float p0 = (lg == 0) ? b3v : 0.f, p1 = 0.f;
#pragma unroll
    for (int r = 0; r < 4; ++r) {
      p0 = fmaf(fmaxf(h3[0][r], 0.f), w3f[0][r], p0);
      p1 = fmaf(fmaxf(h3[1][r], 0.f), w3f[1][r], p1);
    }
    acc[m] += p0 + p1;
  }
  // ---- reduce partials across the 4 lane-groups, store ----
#pragma unroll
  for (int m = 0; m < MT; ++m) {
    float v = acc[m];
    v += __shfl_xor(v, 16, 64);
    v += __shfl_xor(v, 32, 64);
    if (l < 16) part[f * NSAMP + n0 + 16 * m + l] = v;
  }
}

// ---------------------------------------------------------------------------
// Reduce: out[n] = bias + sum_f part[f][n]. float4 over samples, 4-way group
// split + LDS combine. Fixed order -> deterministic.
// ---------------------------------------------------------------------------
__global__ __launch_bounds__(256) void nam_reduce(const float* __restrict__ part,
                                                  const float* __restrict__ bias,
                                                  float* __restrict__ out) {
  int tid = threadIdx.x;
  int quad = blockIdx.x * 64 + (tid & 63);   // which float4 of samples
  int gs = tid >> 6;                         // 0..3 group split
  f32x4 s = {0.f, 0.f, 0.f, 0.f};
#pragma unroll
  for (int g = gs * 32; g < gs * 32 + 32; ++g)
    s += *(const f32x4*)(part + (size_t)g * NSAMP + quad * 4);
  __shared__ f32x4 red[256];
  red[tid] = s;
  __syncthreads();
  if (gs == 0) {
    f32x4 t = red[tid] + red[tid + 64] + red[tid + 128] + red[tid + 192];
    float bv = bias[0];
    t[0] += bv; t[1] += bv; t[2] += bv; t[3] += bv;
    *(f32x4*)(out + quad * 4) = t;
  }
}

// ---------------------------------------------------------------------------
// Fallback (only if ws too small): naive fp32, correct but slow.
// ---------------------------------------------------------------------------
__global__ void nam_naive(const float* __restrict__ X, const float* __restrict__ W0,
                          const float* __restrict__ b0, const float* __restrict__ W1,
                          const float* __restrict__ b1, const float* __restrict__ W2,
                          const float* __restrict__ b2, const float* __restrict__ W3,
                          const float* __restrict__ b3, const float* __restrict__ bias,
                          float* __restrict__ out) {
  int n = blockIdx.x * 64 + threadIdx.x;
  if (n >= NSAMP) return;
  float s = bias[0];
  for (int f = 0; f < NFEAT; ++f) {
    float xv = X[n * NFEAT + f];
    float h1[64], h2[64];
    for (int i = 0; i < 64; ++i)
      h1[i] = fmaxf(fmaf(xv, W0[f * 64 + i], b0[f * 64 + i]), 0.f);
    for (int k = 0; k < 64; ++k) {
      float t = b1[f * 64 + k];
      for (int i = 0; i < 64; ++i) t = fmaf(h1[i], W1[f * 4096 + i * 64 + k], t);
      h2[k] = fmaxf(t, 0.f);
    }
    float c = b3[f];
    for (int k = 0; k < 32; ++k) {
      float t = b2[f * 32 + k];
      for (int i = 0; i < 64; ++i) t = fmaf(h2[i], W2[f * 2048 + i * 32 + k], t);
      c = fmaf(fmaxf(t, 0.f), W3[f * 32 + k], c);
    }
    s += c;
  }
  out[n] = s;
}

extern "C" void kernel_launch(void* const* d_in, const int* in_sizes, int n_in,
                              void* d_out, int out_size, void* d_ws, size_t ws_size,
                              hipStream_t stream) {
  const float* X    = (const float*)d_in[0];
  const float* W0   = (const float*)d_in[1];
  const float* b0   = (const float*)d_in[2];
  const float* W1   = (const float*)d_in[3];
  const float* b1   = (const float*)d_in[4];
  const float* W2   = (const float*)d_in[5];
  const float* b2   = (const float*)d_in[6];
  const float* W3   = (const float*)d_in[7];
  const float* b3   = (const float*)d_in[8];
  const float* bias = (const float*)d_in[9];
  float* out = (float*)d_out;

  const size_t PART_BYTES = (size_t)NFEAT * NSAMP * 4;    // 4 MiB
  if (ws_size < PART_BYTES) {
    nam_naive<<<NSAMP / 64, 64, 0, stream>>>(X, W0, b0, W1, b1, W2, b2, W3, b3, bias, out);
    return;
  }
  float* partb = (float*)d_ws;

  nam_main<<<NFEAT * 16, 256, 0, stream>>>(X, W0, b0, W1, b1, W2, b2, W3, b3, partb);
  nam_reduce<<<(NSAMP / 4) / 64, 256, 0, stream>>>(partb, bias, out);
}